// Round 6
// baseline (563.021 us; speedup 1.0000x reference)
//
#include <hip/hip_runtime.h>
#include <hip/hip_fp16.h>

#define B_ 2
#define L_ 2048
#define D_ 2048
#define H_ 16
#define DH_ 128

typedef _Float16 f16;
typedef _Float16 f16x8 __attribute__((ext_vector_type(8)));
typedef _Float16 f16x4 __attribute__((ext_vector_type(4)));
typedef _Float16 f16x2 __attribute__((ext_vector_type(2)));
typedef float f32x4 __attribute__((ext_vector_type(4)));

__device__ __forceinline__ void gload_lds16(const void* g, void* l) {
  __builtin_amdgcn_global_load_lds(
      (__attribute__((address_space(1))) void*)(void*)g,
      (__attribute__((address_space(3))) void*)l, 16, 0, 0);
}

template <int N>
__device__ __forceinline__ void waitcnt_vm() {
  if constexpr (N == 0) asm volatile("s_waitcnt vmcnt(0)" ::: "memory");
  else if constexpr (N == 4) asm volatile("s_waitcnt vmcnt(4)" ::: "memory");
  else if constexpr (N == 6) asm volatile("s_waitcnt vmcnt(6)" ::: "memory");
  else if constexpr (N == 8) asm volatile("s_waitcnt vmcnt(8)" ::: "memory");
}

__device__ __forceinline__ float rmax16(float v) {
  v = fmaxf(v, __shfl_xor(v, 1));
  v = fmaxf(v, __shfl_xor(v, 2));
  v = fmaxf(v, __shfl_xor(v, 4));
  v = fmaxf(v, __shfl_xor(v, 8));
  return v;
}
__device__ __forceinline__ float rsum16(float v) {
  v += __shfl_xor(v, 1);
  v += __shfl_xor(v, 2);
  v += __shfl_xor(v, 4);
  v += __shfl_xor(v, 8);
  return v;
}

// ---------------- kernel 1: cast x fp32 -> fp16 ----------------
__global__ __launch_bounds__(256) void k_cast(const float* __restrict__ in,
                                              f16* __restrict__ out, int n8) {
  int i = blockIdx.x * blockDim.x + threadIdx.x;
  if (i >= n8) return;
  const float4* p = (const float4*)in + (size_t)i * 2;
  float4 a = p[0], b = p[1];
  f16x8 o;
  o[0] = (f16)a.x; o[1] = (f16)a.y; o[2] = (f16)a.z; o[3] = (f16)a.w;
  o[4] = (f16)b.x; o[5] = (f16)b.y; o[6] = (f16)b.z; o[7] = (f16)b.w;
  *((f16x8*)out + i) = o;
}

// ------- kernel 2: transpose+cast 2048x2048 fp32 -> fp16 (N x K) -------
__global__ __launch_bounds__(256) void k_transpose4(
    const float* __restrict__ W0, const float* __restrict__ W1,
    const float* __restrict__ W2, const float* __restrict__ W3,
    f16* __restrict__ T0, f16* __restrict__ T1, f16* __restrict__ T2,
    f16* __restrict__ T3) {
  int z = blockIdx.z;
  const float* src = (z == 0) ? W0 : (z == 1) ? W1 : (z == 2) ? W2 : W3;
  f16* dst = (z == 0) ? T0 : (z == 1) ? T1 : (z == 2) ? T2 : T3;
  __shared__ float tile[32][33];
  int tx = threadIdx.x, ty = threadIdx.y;
  int x = blockIdx.x * 32 + tx;
  int y0 = blockIdx.y * 32;
#pragma unroll
  for (int i = 0; i < 4; ++i)
    tile[ty + i * 8][tx] = src[(size_t)(y0 + ty + i * 8) * 2048 + x];
  __syncthreads();
  int ox = y0 + tx;
  int oy0 = blockIdx.x * 32;
#pragma unroll
  for (int i = 0; i < 4; ++i)
    dst[(size_t)(oy0 + ty + i * 8) * 2048 + ox] = (f16)tile[tx][ty + i * 8];
}

// stage NL*512 16B-chunks: linear LDS dest, inverse-swizzled global source.
template <int NL>
__device__ __forceinline__ void stage_slot(const char* __restrict__ src,
                                           char* dst, int tid) {
#pragma unroll
  for (int j = 0; j < NL; ++j) {
    int ci = j * 512 + tid;
    int row = ci >> 3;
    int sc = (ci & 7) ^ (row & 7);
    gload_lds16(src + (size_t)row * 4096 + sc * 16, dst + ci * 16);
  }
}

// ======== qkv GEMM: BM=128, BN=384 (fused q|k|v), BK=64, 8 waves, 3 phases ========
__global__ __launch_bounds__(512, 2) void k_gemm8_qkv(
    const f16* __restrict__ x16, const f16* __restrict__ WT /* [6144][2048] */,
    f16* __restrict__ qh, f16* __restrict__ kh, f16* __restrict__ vTo) {
  constexpr int ABYTES = 128 * 128;          // 16 KiB
  constexpr int BUFB = ABYTES + 384 * 128;   // 64 KiB
  constexpr int nt = 32;
  __shared__ alignas(16) char lds[2 * BUFB]; // 128 KiB

  const int pb = blockIdx.x;                  // 0..511 (512 % 8 == 0)
  const int lgc = (pb & 7) * 64 + (pb >> 3);  // bijective XCD chunking
  const int m0 = (lgc & 31) * 128;            // n-major within XCD chunk:
  const int n0 = (lgc >> 5) * 384;            // per-XCD B traffic 24->3 MB

  const int tid = threadIdx.x;
  const int lane = tid & 63, w = tid >> 6;
  const int wr = w >> 2, wc = w & 3;          // 2M x 4N waves
  const int li = lane & 15, lg = lane >> 4;

  const char* Ab = (const char*)x16 + (size_t)m0 * 4096;
  const char* Bb = (const char*)WT + (size_t)n0 * 4096;

  f32x4 acc[4][6] = {};

  // prologue: tiles 0,1
#pragma unroll
  for (int t = 0; t < 2; ++t) {
    char* bA = lds + t * BUFB;
    stage_slot<2>(Ab + t * 128, bA, tid);
    stage_slot<6>(Bb + t * 128, bA + ABYTES, tid);
  }
  waitcnt_vm<8>();
  __builtin_amdgcn_s_barrier();

  const int sx = (li & 7);  // row&7 for all frag rows (row == li mod 8)

#pragma unroll 1
  for (int u = 0; u < nt; ++u) {
    const int c = u & 1;
    char* bufA = lds + c * BUFB;
    char* bufB = bufA + ABYTES;
    char* oA = lds + (c ^ 1) * BUFB;
    f16x8 af[4][2], bf[6][2];

    // ---- phase 0: read A frags + B frags nc 0,1; stage A(u+1); MFMA nc 0,1 ----
#pragma unroll
    for (int mr = 0; mr < 4; ++mr) {
      int rb = (wr * 64 + mr * 16 + li) * 128;
      af[mr][0] = *(const f16x8*)(bufA + rb + ((lg ^ sx) << 4));
      af[mr][1] = *(const f16x8*)(bufA + rb + (((4 + lg) ^ sx) << 4));
    }
#pragma unroll
    for (int nc = 0; nc < 2; ++nc) {
      int rb = (wc * 96 + nc * 16 + li) * 128;
      bf[nc][0] = *(const f16x8*)(bufB + rb + ((lg ^ sx) << 4));
      bf[nc][1] = *(const f16x8*)(bufB + rb + (((4 + lg) ^ sx) << 4));
    }
    if (u >= 1 && u + 1 < nt) stage_slot<2>(Ab + (size_t)(u + 1) * 128, oA, tid);
    __builtin_amdgcn_s_barrier();
    asm volatile("s_waitcnt lgkmcnt(0)" ::: "memory");
    __builtin_amdgcn_sched_barrier(0);
    __builtin_amdgcn_s_setprio(1);
#pragma unroll
    for (int mr = 0; mr < 4; ++mr)
#pragma unroll
      for (int nc = 0; nc < 2; ++nc) {
        acc[mr][nc] = __builtin_amdgcn_mfma_f32_16x16x32_f16(af[mr][0], bf[nc][0],
                                                             acc[mr][nc], 0, 0, 0);
        acc[mr][nc] = __builtin_amdgcn_mfma_f32_16x16x32_f16(af[mr][1], bf[nc][1],
                                                             acc[mr][nc], 0, 0, 0);
      }
    __builtin_amdgcn_s_setprio(0);
    __builtin_amdgcn_s_barrier();

    // ---- phase 1: read B frags nc 2..5; MFMA nc 2,3 ----
#pragma unroll
    for (int nc = 2; nc < 6; ++nc) {
      int rb = (wc * 96 + nc * 16 + li) * 128;
      bf[nc][0] = *(const f16x8*)(bufB + rb + ((lg ^ sx) << 4));
      bf[nc][1] = *(const f16x8*)(bufB + rb + (((4 + lg) ^ sx) << 4));
    }
    __builtin_amdgcn_s_barrier();
    asm volatile("s_waitcnt lgkmcnt(0)" ::: "memory");
    __builtin_amdgcn_sched_barrier(0);
    __builtin_amdgcn_s_setprio(1);
#pragma unroll
    for (int mr = 0; mr < 4; ++mr)
#pragma unroll
      for (int nc = 2; nc < 4; ++nc) {
        acc[mr][nc] = __builtin_amdgcn_mfma_f32_16x16x32_f16(af[mr][0], bf[nc][0],
                                                             acc[mr][nc], 0, 0, 0);
        acc[mr][nc] = __builtin_amdgcn_mfma_f32_16x16x32_f16(af[mr][1], bf[nc][1],
                                                             acc[mr][nc], 0, 0, 0);
      }
    __builtin_amdgcn_s_setprio(0);
    __builtin_amdgcn_s_barrier();

    // ---- phase 2: stage B(u+2) into current bufB (reads done); MFMA nc 4,5 ----
    if (u + 2 < nt) stage_slot<6>(Bb + (size_t)(u + 2) * 128, bufB, tid);
    if (u + 2 < nt) waitcnt_vm<6>();
    else if (u + 1 < nt) waitcnt_vm<0>();
    __builtin_amdgcn_s_barrier();
    __builtin_amdgcn_sched_barrier(0);
    __builtin_amdgcn_s_setprio(1);
#pragma unroll
    for (int mr = 0; mr < 4; ++mr)
#pragma unroll
      for (int nc = 4; nc < 6; ++nc) {
        acc[mr][nc] = __builtin_amdgcn_mfma_f32_16x16x32_f16(af[mr][0], bf[nc][0],
                                                             acc[mr][nc], 0, 0, 0);
        acc[mr][nc] = __builtin_amdgcn_mfma_f32_16x16x32_f16(af[mr][1], bf[nc][1],
                                                             acc[mr][nc], 0, 0, 0);
      }
    __builtin_amdgcn_s_setprio(0);
    __builtin_amdgcn_s_barrier();
  }

  // epilogue: n -> (z, h, dh); z<2 scalar head-major, z==2 v-transposed f16x4
#pragma unroll
  for (int mr = 0; mr < 4; ++mr) {
    int mb = m0 + wr * 64 + mr * 16 + lg * 4;   // multiple of 4
    int b = mb >> 11, l = mb & 2047;
#pragma unroll
    for (int nc = 0; nc < 6; ++nc) {
      int n = n0 + wc * 96 + nc * 16 + li;
      int z = n >> 11, n2 = n & 2047;
      int h = n2 >> 7, dh = n2 & 127;
      if (z < 2) {
        f16* out = (z == 0) ? qh : kh;
#pragma unroll
        for (int r2 = 0; r2 < 4; ++r2) {
          int m = mb + r2;
          out[(((size_t)(b * 16 + h) * 2048 + (m & 2047)) << 7) + dh] =
              (f16)acc[mr][nc][r2];
        }
      } else {
        f16x4 v4;
#pragma unroll
        for (int r2 = 0; r2 < 4; ++r2) v4[r2] = (f16)acc[mr][nc][r2];
        *(f16x4*)(vTo + ((size_t)(b * 16 + h) * 128 + dh) * 2048 + l) = v4;
      }
    }
  }
}

// ======== 4-phase GEMM core for gemm_out ========
template <int BM>
__device__ __forceinline__ void gemm8_core(const f16* __restrict__ A,
                                           const f16* __restrict__ BT,
                                           char* lds, int m0, int n0,
                                           f32x4 (&acc)[BM / 32][4]) {
  constexpr int WRS = BM / 2;
  constexpr int MR = BM / 32;
  constexpr int MPP = MR / 4;
  constexpr int ALOADS = BM / 128;
  constexpr int LPT = 2 * ALOADS + 4;
  constexpr int ABYTES = BM * 128;
  constexpr int BUFB = ABYTES + 32768;
  constexpr int nt = 32;

  const int tid = threadIdx.x;
  const int lane = tid & 63, w = tid >> 6;
  const int wr = w >> 2, wc = w & 3;
  const int li = lane & 15, lg = lane >> 4;

  const char* Ab = (const char*)A + (size_t)m0 * 4096;
  const char* Bb = (const char*)BT + (size_t)n0 * 4096;

  const int aoff0 = (wr * WRS + li) * 128 + ((lg) ^ (li & 7)) * 16;
  const int aoff1 = (wr * WRS + li) * 128 + ((4 + lg) ^ (li & 7)) * 16;
  const int boff0 = (wc * 64 + li) * 128 + ((lg) ^ (li & 7)) * 16;
  const int boff1 = (wc * 64 + li) * 128 + ((4 + lg) ^ (li & 7)) * 16;

#pragma unroll
  for (int t = 0; t < 2; ++t) {
    char* bA = lds + t * BUFB;
    stage_slot<ALOADS>(Ab + t * 128, bA, tid);
    stage_slot<ALOADS>(Ab + (size_t)WRS * 4096 + t * 128, bA + (size_t)WRS * 128, tid);
    stage_slot<2>(Bb + t * 128, bA + ABYTES, tid);
    stage_slot<2>(Bb + (size_t)128 * 4096 + t * 128, bA + ABYTES + 128 * 128, tid);
  }
  waitcnt_vm<LPT>();
  __builtin_amdgcn_s_barrier();

#pragma unroll 1
  for (int u = 0; u < nt; ++u) {
    const int c = u & 1;
    char* bufA = lds + c * BUFB;
    char* bufB = bufA + ABYTES;
    char* oA = lds + (c ^ 1) * BUFB;
    f16x8 bf[4][2];
#pragma unroll
    for (int p = 0; p < 4; ++p) {
      f16x8 af[MPP][2];
#pragma unroll
      for (int i = 0; i < MPP; ++i) {
        af[i][0] = *(const f16x8*)(bufA + aoff0 + (p * MPP + i) * 2048);
        af[i][1] = *(const f16x8*)(bufA + aoff1 + (p * MPP + i) * 2048);
      }
      if (p == 0) {
#pragma unroll
        for (int nc = 0; nc < 4; ++nc) {
          bf[nc][0] = *(const f16x8*)(bufB + boff0 + nc * 2048);
          bf[nc][1] = *(const f16x8*)(bufB + boff1 + nc * 2048);
        }
      }
      if (p == 0 && u >= 1 && u + 1 < nt)
        stage_slot<ALOADS>(Ab + (size_t)(u + 1) * 128, oA, tid);
      if (p == 1 && u >= 1 && u + 1 < nt)
        stage_slot<ALOADS>(Ab + (size_t)WRS * 4096 + (size_t)(u + 1) * 128,
                           oA + (size_t)WRS * 128, tid);
      if (p == 2 && u + 2 < nt)
        stage_slot<2>(Bb + (size_t)(u + 2) * 128, bufB, tid);
      if (p == 3 && u + 2 < nt)
        stage_slot<2>(Bb + (size_t)128 * 4096 + (size_t)(u + 2) * 128,
                      bufB + 128 * 128, tid);
      if (p == 3) {
        if (u + 2 < nt) waitcnt_vm<4>();
        else if (u + 1 < nt) waitcnt_vm<0>();
      }
      __builtin_amdgcn_s_barrier();
      asm volatile("s_waitcnt lgkmcnt(0)" ::: "memory");
      __builtin_amdgcn_sched_barrier(0);
      __builtin_amdgcn_s_setprio(1);
#pragma unroll
      for (int i = 0; i < MPP; ++i)
#pragma unroll
        for (int nc = 0; nc < 4; ++nc) {
          acc[p * MPP + i][nc] = __builtin_amdgcn_mfma_f32_16x16x32_f16(
              af[i][0], bf[nc][0], acc[p * MPP + i][nc], 0, 0, 0);
          acc[p * MPP + i][nc] = __builtin_amdgcn_mfma_f32_16x16x32_f16(
              af[i][1], bf[nc][1], acc[p * MPP + i][nc], 0, 0, 0);
        }
      __builtin_amdgcn_s_setprio(0);
      __builtin_amdgcn_s_barrier();
    }
  }
}

// --------- kernel 6: output projection (BM=128/BN=256 -> 256 blocks) ---------
__global__ __launch_bounds__(512, 2) void k_gemm8_out(
    const f16* __restrict__ A, const f16* __restrict__ WoutT,
    float* __restrict__ out) {
  __shared__ alignas(16) char lds[2 * (128 * 128 + 32768)];  // 96 KiB
  const int pb = blockIdx.x;
  const int lgc = (pb & 7) * 32 + (pb >> 3);
  const int m0 = (lgc >> 3) * 128, n0 = (lgc & 7) * 256;
  f32x4 acc[4][4] = {};
  gemm8_core<128>(A, WoutT, lds, m0, n0, acc);

  const int lane = threadIdx.x & 63, w = threadIdx.x >> 6;
  const int wr = w >> 2, wc = w & 3, li = lane & 15, lg = lane >> 4;
#pragma unroll
  for (int mr = 0; mr < 4; ++mr) {
#pragma unroll
    for (int nc = 0; nc < 4; ++nc) {
      int n = n0 + wc * 64 + nc * 16 + li;
#pragma unroll
      for (int r2 = 0; r2 < 4; ++r2) {
        int m = m0 + wr * 64 + mr * 16 + lg * 4 + r2;
        out[(size_t)m * 2048 + n] = acc[mr][nc][r2];
      }
    }
  }
}

// ---------------- kernel 4: RoPE + L2 normalize, in place on qh/kh ----------------
__global__ __launch_bounds__(256) void k_rope_norm(f16* __restrict__ qh,
                                                   f16* __restrict__ kh) {
  int gid = blockIdx.x * 4 + (threadIdx.x >> 6);
  int lane = threadIdx.x & 63;
  int which = gid >> 16;
  int r = gid & 65535;
  int l = r & 2047;
  f16* base = (which ? kh : qh) + (size_t)r * 128;
  f16x2 xv = *(f16x2*)(base + lane * 2);
  float x0 = (float)xv[0], x1 = (float)xv[1];
  float invf = exp2f(-(float)lane * 0.29580575889569f);
  float ang = (float)l * invf;
  float s, c;
  sincosf(ang, &s, &c);
  float y0 = x0 * c - x1 * s;
  float y1 = x1 * c + x0 * s;
  float ss = y0 * y0 + y1 * y1;
  ss += __shfl_xor(ss, 1);  ss += __shfl_xor(ss, 2);
  ss += __shfl_xor(ss, 4);  ss += __shfl_xor(ss, 8);
  ss += __shfl_xor(ss, 16); ss += __shfl_xor(ss, 32);
  float inv = 1.0f / (sqrtf(ss) + 1e-6f);
  f16x2 o;
  o[0] = (f16)(y0 * inv);
  o[1] = (f16)(y1 * inv);
  *(f16x2*)(base + lane * 2) = o;
}

// ---------------- kernel 5: flash attention, direct K/V reg loads ----------------
// K/V are L2-resident per bh (1 MB); each tile is read ONCE per block, so LDS
// staging was pure overhead (guide common-mistake #7). No barriers in k-loop:
// waves run free, MFMA/VALU overlap across 8+ waves/CU.
__global__ __launch_bounds__(256) void k_flash(
    const f16* __restrict__ qh, const f16* __restrict__ kh,
    const f16* __restrict__ vT, f16* __restrict__ attO,
    const float* __restrict__ ascale_p) {
  const int bh = blockIdx.y;
  const int tid = threadIdx.x, lane = tid & 63, w = tid >> 6;
  const int li = lane & 15, lg = lane >> 4;
  const float csc = ascale_p[0] * 1.44269504088896f;
  const float thr = 8.0f / csc;

  __shared__ alignas(16) f16 Ps[4][16 * 72];   // wave-private P relayout

  const f16* qb = qh + (size_t)bh * 2048 * 128;
  const f16* kb = kh + (size_t)bh * 2048 * 128;
  const f16* vb = vT + (size_t)bh * 128 * 2048;
  const int b = bh >> 4, h = bh & 15;

#pragma unroll 1
  for (int ti = 0; ti < 2; ++ti) {
    const int t = ti ? (31 - (int)blockIdx.x) : (int)blockIdx.x;
    const int qw = t * 64 + w * 16;

    f16x8 Qr[4];
#pragma unroll
    for (int ks = 0; ks < 4; ++ks)
      Qr[ks] = *(const f16x8*)(qb + (size_t)(qw + li) * 128 + ks * 32 + lg * 8);

    f32x4 Oa[8] = {};
    float mrow[4], lrow[4];
#pragma unroll
    for (int r = 0; r < 4; ++r) { mrow[r] = -1e30f; lrow[r] = 0.0f; }

#pragma unroll 1
    for (int kt = 0; kt <= t; ++kt) {
      const f16* kbase = kb + (size_t)kt * 64 * 128;
      const f16* vbase = vb + kt * 64;

      // S = Q K^T  (K frags direct from global; L2-hit)
      f32x4 Sa[4] = {};
      __builtin_amdgcn_s_setprio(1);
#pragma unroll
      for (int ks = 0; ks < 4; ++ks) {
        f16x8 kf4[4];
#pragma unroll
        for (int kf = 0; kf < 4; ++kf)
          kf4[kf] = *(const f16x8*)(kbase + (kf * 16 + li) * 128 + ks * 32 + lg * 8);
#pragma unroll
        for (int kf = 0; kf < 4; ++kf)
          Sa[kf] = __builtin_amdgcn_mfma_f32_16x16x32_f16(Qr[ks], kf4[kf],
                                                          Sa[kf], 0, 0, 0);
      }
      __builtin_amdgcn_s_setprio(0);

      if (kt == t) {  // diagonal: causal mask
#pragma unroll
        for (int kf = 0; kf < 4; ++kf)
#pragma unroll
          for (int r = 0; r < 4; ++r) {
            int qq = qw + lg * 4 + r;
            int kk = t * 64 + kf * 16 + li;
            if (kk > qq) Sa[kf][r] = -1e30f;
          }
      }

      float vmax[4];
      bool need = false;
#pragma unroll
      for (int r = 0; r < 4; ++r) {
        float v = fmaxf(fmaxf(Sa[0][r], Sa[1][r]), fmaxf(Sa[2][r], Sa[3][r]));
        v = rmax16(v);
        vmax[r] = v;
        need |= (v > mrow[r] + thr);
      }
      if (__any(need)) {
#pragma unroll
        for (int r = 0; r < 4; ++r) {
          float mnew = fmaxf(mrow[r], vmax[r]);
          float sc = exp2f(csc * (mrow[r] - mnew));
          mrow[r] = mnew;
          lrow[r] *= sc;
#pragma unroll
          for (int df = 0; df < 8; ++df) Oa[df][r] *= sc;
        }
      }
#pragma unroll
      for (int r = 0; r < 4; ++r) {
        float rs = 0.0f;
#pragma unroll
        for (int kf = 0; kf < 4; ++kf) {
          float p = exp2f(csc * (Sa[kf][r] - mrow[r]));
          Sa[kf][r] = p;
          rs += p;
        }
        rs = rsum16(rs);
        lrow[r] += rs;
      }

      // P -> LDS (wave-private), then PV with V frags direct from global
      f16* Pw = &Ps[w][0];
#pragma unroll
      for (int kf = 0; kf < 4; ++kf)
#pragma unroll
        for (int r = 0; r < 4; ++r)
          Pw[(lg * 4 + r) * 72 + kf * 16 + li] = (f16)Sa[kf][r];
      asm volatile("s_waitcnt lgkmcnt(0)" ::: "memory");
      __builtin_amdgcn_sched_barrier(0);
      __builtin_amdgcn_s_setprio(1);
#pragma unroll
      for (int k2 = 0; k2 < 2; ++k2) {
        f16x8 pa, vfr[8];
        pa = *(const f16x8*)(Pw + li * 72 + k2 * 32 + lg * 8);
#pragma unroll
        for (int df = 0; df < 8; ++df)
          vfr[df] = *(const f16x8*)(vbase + (size_t)(df * 16 + li) * 2048 +
                                    k2 * 32 + lg * 8);
#pragma unroll
        for (int df = 0; df < 8; ++df)
          Oa[df] = __builtin_amdgcn_mfma_f32_16x16x32_f16(pa, vfr[df],
                                                          Oa[df], 0, 0, 0);
      }
      __builtin_amdgcn_s_setprio(0);
    }

    // epilogue: O /= l, write (B,L,H*Dh) fp16
#pragma unroll
    for (int r = 0; r < 4; ++r) {
      float inv = 1.0f / lrow[r];
      int q = qw + lg * 4 + r;
      f16* orow = attO + (size_t)(b * 2048 + q) * 2048 + h * 128;
#pragma unroll
      for (int df = 0; df < 8; ++df)
        orow[df * 16 + li] = (f16)(Oa[df][r] * inv);
    }
  }
}

extern "C" void kernel_launch(void* const* d_in, const int* in_sizes, int n_in,
                              void* d_out, int out_size, void* d_ws, size_t ws_size,
                              hipStream_t stream) {
  (void)in_sizes; (void)n_in; (void)out_size; (void)ws_size;
  const float* x = (const float*)d_in[0];
  const float* Wq = (const float*)d_in[1];
  const float* Wk = (const float*)d_in[2];
  const float* Wv = (const float*)d_in[3];
  const float* Wout = (const float*)d_in[4];
  const float* ascale = (const float*)d_in[5];

  char* ws = (char*)d_ws;
  f16* x16 = (f16*)(ws);                       // 16 MB
  f16* WoutT = (f16*)(ws + (16ull << 20));     // 8 MB
  f16* WqT = (f16*)(ws + (24ull << 20));       // 8 MB, first third of [6144][2048]
  f16* WkT = (f16*)(ws + (32ull << 20));       // 8 MB, second third (contiguous)
  f16* WvT = (f16*)(ws + (40ull << 20));       // 8 MB, last third (contiguous)
  f16* qh = (f16*)(ws + (48ull << 20));        // 16 MB  (B,H,L,Dh)
  f16* kh = (f16*)(ws + (64ull << 20));        // 16 MB
  f16* vT = (f16*)(ws + (80ull << 20));        // 16 MB  (B,H,Dh,L)
  f16* attO = (f16*)(ws + (24ull << 20));      // 16 MB, aliases WqT/WkT (dead by then)

  k_cast<<<dim3(4096), dim3(256), 0, stream>>>(x, x16, 1048576);
  k_transpose4<<<dim3(64, 64, 4), dim3(32, 8), 0, stream>>>(Wq, Wk, Wv, Wout,
                                                            WqT, WkT, WvT, WoutT);
  k_gemm8_qkv<<<dim3(512), dim3(512), 0, stream>>>(x16, WqT, qh, kh, vT);
  k_rope_norm<<<dim3(32768), dim3(256), 0, stream>>>(qh, kh);
  k_flash<<<dim3(16, 32), dim3(256), 0, stream>>>(qh, kh, vT, attO, ascale);
  k_gemm8_out<<<dim3(256), dim3(512), 0, stream>>>(attO, WoutT, (float*)d_out);
}